// Round 1
// baseline (1007.823 us; speedup 1.0000x reference)
//
#include <hip/hip_runtime.h>

#define NEG_SLOPE 0.2f

__device__ __forceinline__ float lrelu(float x) { return x > 0.f ? x : NEG_SLOPE * x; }

// ---------------- CSR build ----------------

__global__ void k_deg(const int* __restrict__ dst, int E, int* __restrict__ deg) {
    int e = blockIdx.x * blockDim.x + threadIdx.x;
    if (e < E) atomicAdd(&deg[dst[e]], 1);
}

// exclusive scan within blocks of 1024; emits per-block totals
__global__ void k_scan1(const int* __restrict__ in, int n, int* __restrict__ out,
                        int* __restrict__ bsum) {
    __shared__ int sd[1024];
    int tid = threadIdx.x;
    int i = blockIdx.x * 1024 + tid;
    int v = (i < n) ? in[i] : 0;
    sd[tid] = v;
    __syncthreads();
    for (int off = 1; off < 1024; off <<= 1) {
        int t = (tid >= off) ? sd[tid - off] : 0;
        __syncthreads();
        sd[tid] += t;
        __syncthreads();
    }
    if (i < n) out[i] = sd[tid] - v;          // exclusive
    if (tid == 0) bsum[blockIdx.x] = sd[1023]; // block total
}

// exclusive scan of up to 128 block sums, in place
__global__ void k_scan2(int* __restrict__ bs, int nb) {
    __shared__ int sd[128];
    int tid = threadIdx.x;
    int v = (tid < nb) ? bs[tid] : 0;
    sd[tid] = v;
    __syncthreads();
    for (int off = 1; off < 128; off <<= 1) {
        int t = (tid >= off) ? sd[tid - off] : 0;
        __syncthreads();
        sd[tid] += t;
        __syncthreads();
    }
    if (tid < nb) bs[tid] = sd[tid] - v;
}

__global__ void k_scan3(const int* __restrict__ scanned, const int* __restrict__ bsum,
                        int n, int E, int* __restrict__ offs, int* __restrict__ cursor) {
    int i = blockIdx.x * blockDim.x + threadIdx.x;
    if (i < n) {
        int o = scanned[i] + bsum[i >> 10];
        offs[i] = o;
        cursor[i] = o;
    }
    if (i == 0) offs[n] = E;
}

__global__ void k_scatter(const int* __restrict__ src, const int* __restrict__ dst, int E,
                          int* __restrict__ cursor, int* __restrict__ adj) {
    int e = blockIdx.x * blockDim.x + threadIdx.x;
    if (e < E) {
        int d = dst[e];
        int p = atomicAdd(&cursor[d], 1);
        adj[p] = src[e];
    }
}

// ---------------- GAT layer kernels ----------------
// One wave (64 lanes) per node; 4 nodes per 256-thread block.

// layer 0 projection: h = concat(pos,x) [N,32] @ W[32,64]; also s = hp.att_src, d = hp.att_dst
__global__ void k_mm0(const float* __restrict__ pos, const float* __restrict__ x,
                      const float* __restrict__ W, const float* __restrict__ asrc,
                      const float* __restrict__ adst, int n, float* __restrict__ hp,
                      float* __restrict__ s, float* __restrict__ d) {
    int lane = threadIdx.x & 63;
    int node = blockIdx.x * 4 + (threadIdx.x >> 6);
    if (node >= n) return;
    const float* pr = pos + (size_t)node * 2;
    const float* xr = x + (size_t)node * 30;
    float acc = 0.f;
#pragma unroll
    for (int k = 0; k < 2; k++) acc += pr[k] * W[k * 64 + lane];
#pragma unroll
    for (int k = 0; k < 30; k++) acc += xr[k] * W[(k + 2) * 64 + lane];
    hp[(size_t)node * 64 + lane] = acc;
    float sv = acc * asrc[lane];
    float dv = acc * adst[lane];
#pragma unroll
    for (int off = 32; off; off >>= 1) {
        sv += __shfl_xor(sv, off);
        dv += __shfl_xor(dv, off);
    }
    if (lane == 0) {
        s[node] = sv;
        d[node] = dv;
    }
}

// layer 1 projection: h [N,64] @ W[64,64]
__global__ void k_mm(const float* __restrict__ h, const float* __restrict__ W,
                     const float* __restrict__ asrc, const float* __restrict__ adst, int n,
                     float* __restrict__ hp, float* __restrict__ s, float* __restrict__ d) {
    int lane = threadIdx.x & 63;
    int node = blockIdx.x * 4 + (threadIdx.x >> 6);
    if (node >= n) return;
    const float* hr = h + (size_t)node * 64;
    float acc = 0.f;
#pragma unroll
    for (int k = 0; k < 64; k++) acc += hr[k] * W[k * 64 + lane];
    hp[(size_t)node * 64 + lane] = acc;
    float sv = acc * asrc[lane];
    float dv = acc * adst[lane];
#pragma unroll
    for (int off = 32; off; off >>= 1) {
        sv += __shfl_xor(sv, off);
        dv += __shfl_xor(dv, off);
    }
    if (lane == 0) {
        s[node] = sv;
        d[node] = dv;
    }
}

// gather aggregation: softmax over in-edges (incl. self loop), weighted sum of hp rows
__global__ void k_agg(const int* __restrict__ offs, const int* __restrict__ adj,
                      const float* __restrict__ hp, const float* __restrict__ s,
                      const float* __restrict__ dd, const float* __restrict__ bias, int n,
                      float* __restrict__ out) {
    int lane = threadIdx.x & 63;
    int node = blockIdx.x * 4 + (threadIdx.x >> 6);
    if (node >= n) return;
    float di = dd[node];
    int e0 = offs[node], e1 = offs[node + 1];
    // pass 1: max (self loop + in-edges), for softmax stability (matches reference)
    float m = lrelu(s[node] + di);
    for (int e = e0; e < e1; e++) m = fmaxf(m, lrelu(s[adj[e]] + di));
    // pass 2: exp + accumulate
    float w = expf(lrelu(s[node] + di) - m);
    float wsum = w;
    float acc = hp[(size_t)node * 64 + lane] * w;
    for (int e = e0; e < e1; e++) {
        int j = adj[e];
        float wj = expf(lrelu(s[j] + di) - m);
        wsum += wj;
        acc += hp[(size_t)j * 64 + lane] * wj;
    }
    out[(size_t)node * 64 + lane] = acc / wsum + bias[lane];
}

// ---------------- pooling + head ----------------

__global__ void k_pool(const float* __restrict__ h, const int* __restrict__ batch, int n,
                       float* __restrict__ out) {
    __shared__ float red[256];
    int gid = blockIdx.x;
    int tid = threadIdx.x;
    int lane = tid & 63;
    int wv = tid >> 6;
    // lower_bound(batch, gid) and lower_bound(batch, gid+1); batch is sorted
    int lo = 0, hi = n;
    while (lo < hi) {
        int md = (lo + hi) >> 1;
        if (batch[md] < gid) lo = md + 1; else hi = md;
    }
    int start = lo;
    lo = 0; hi = n;
    while (lo < hi) {
        int md = (lo + hi) >> 1;
        if (batch[md] < gid + 1) lo = md + 1; else hi = md;
    }
    int end = lo;
    float acc = 0.f;
    for (int i = start + wv; i < end; i += 4) acc += h[(size_t)i * 64 + lane];
    red[tid] = acc;
    __syncthreads();
    if (tid < 64) {
        float sum = red[tid] + red[tid + 64] + red[tid + 128] + red[tid + 192];
        float cnt = (float)(end - start);
        out[gid * 64 + tid] = sum / fmaxf(cnt, 1.f);
    }
}

__global__ void k_head(const float* __restrict__ g, const float* __restrict__ W0,
                       const float* __restrict__ b0, const float* __restrict__ W1,
                       const float* __restrict__ b1, float* __restrict__ out) {
    __shared__ float gs[64];
    __shared__ float mid[32];
    int i = blockIdx.x;
    int t = threadIdx.x;
    gs[t] = g[i * 64 + t];
    __syncthreads();
    if (t < 32) {
        float a = b0[t];
#pragma unroll
        for (int k = 0; k < 64; k++) a += gs[k] * W0[k * 32 + t];
        mid[t] = fmaxf(a, 0.f);
    }
    __syncthreads();
    if (t < 10) {
        float a = b1[t];
#pragma unroll
        for (int k = 0; k < 32; k++) a += mid[k] * W1[k * 10 + t];
        out[i * 10 + t] = fmaxf(a, 0.f);
    }
}

// ---------------- launch ----------------

extern "C" void kernel_launch(void* const* d_in, const int* in_sizes, int n_in,
                              void* d_out, int out_size, void* d_ws, size_t ws_size,
                              hipStream_t stream) {
    const float* x    = (const float*)d_in[0];
    const float* pos  = (const float*)d_in[1];
    const int*   ei   = (const int*)d_in[2];
    const int*   batch= (const int*)d_in[3];
    const float* g0W  = (const float*)d_in[4];
    const float* g0as = (const float*)d_in[5];
    const float* g0ad = (const float*)d_in[6];
    const float* g0b  = (const float*)d_in[7];
    const float* g1W  = (const float*)d_in[8];
    const float* g1as = (const float*)d_in[9];
    const float* g1ad = (const float*)d_in[10];
    const float* g1b  = (const float*)d_in[11];
    const float* l0W  = (const float*)d_in[12];
    const float* l0b  = (const float*)d_in[13];
    const float* l1W  = (const float*)d_in[14];
    const float* l1b  = (const float*)d_in[15];
    float* out = (float*)d_out;

    const int N = in_sizes[3];       // 100000
    const int E = in_sizes[2] / 2;   // 1600000
    const int G = out_size / 10;     // 64

    // workspace carve-up (256B aligned)
    char* w = (char*)d_ws;
    auto alloc = [&](size_t bytes) {
        void* p = (void*)w;
        w += (bytes + 255) & ~(size_t)255;
        return p;
    };
    int* deg     = (int*)alloc((size_t)N * 4);
    int* scanned = (int*)alloc((size_t)N * 4);
    int* bsum    = (int*)alloc(128 * 4);
    int* offs    = (int*)alloc((size_t)(N + 1) * 4);
    int* cursor  = (int*)alloc((size_t)N * 4);
    int* adj     = (int*)alloc((size_t)E * 4);
    float* hp    = (float*)alloc((size_t)N * 64 * 4);
    float* hbuf  = (float*)alloc((size_t)N * 64 * 4);
    float* sarr  = (float*)alloc((size_t)N * 4);
    float* darr  = (float*)alloc((size_t)N * 4);
    float* gpool = (float*)alloc((size_t)G * 64 * 4);

    const int* esrc = ei;
    const int* edst = ei + E;

    // CSR build (shared by both layers)
    hipMemsetAsync(deg, 0, (size_t)N * 4, stream);
    k_deg<<<(E + 255) / 256, 256, 0, stream>>>(edst, E, deg);
    int nb1 = (N + 1023) / 1024; // 98 <= 128
    k_scan1<<<nb1, 1024, 0, stream>>>(deg, N, scanned, bsum);
    k_scan2<<<1, 128, 0, stream>>>(bsum, nb1);
    k_scan3<<<(N + 255) / 256, 256, 0, stream>>>(scanned, bsum, N, E, offs, cursor);
    k_scatter<<<(E + 255) / 256, 256, 0, stream>>>(esrc, edst, E, cursor, adj);

    int nodeBlocks = (N + 3) / 4;
    // layer 0
    k_mm0<<<nodeBlocks, 256, 0, stream>>>(pos, x, g0W, g0as, g0ad, N, hp, sarr, darr);
    k_agg<<<nodeBlocks, 256, 0, stream>>>(offs, adj, hp, sarr, darr, g0b, N, hbuf);
    // layer 1
    k_mm<<<nodeBlocks, 256, 0, stream>>>(hbuf, g1W, g1as, g1ad, N, hp, sarr, darr);
    k_agg<<<nodeBlocks, 256, 0, stream>>>(offs, adj, hp, sarr, darr, g1b, N, hbuf);
    // pool + head
    k_pool<<<G, 256, 0, stream>>>(hbuf, batch, N, gpool);
    k_head<<<G, 64, 0, stream>>>(gpool, l0W, l0b, l1W, l1b, out);
}

// Round 2
// 713.803 us; speedup vs baseline: 1.4119x; 1.4119x over previous
//
#include <hip/hip_runtime.h>

#define NEG_SLOPE 0.2f

__device__ __forceinline__ float lrelu(float x) { return x > 0.f ? x : NEG_SLOPE * x; }

// ---------------- CSR build ----------------

__global__ void k_deg(const int* __restrict__ dst, int E, int* __restrict__ deg) {
    int e = blockIdx.x * blockDim.x + threadIdx.x;
    if (e < E) atomicAdd(&deg[dst[e]], 1);
}

// exclusive scan within blocks of 1024; emits per-block totals
__global__ void k_scan1(const int* __restrict__ in, int n, int* __restrict__ out,
                        int* __restrict__ bsum) {
    __shared__ int sd[1024];
    int tid = threadIdx.x;
    int i = blockIdx.x * 1024 + tid;
    int v = (i < n) ? in[i] : 0;
    sd[tid] = v;
    __syncthreads();
    for (int off = 1; off < 1024; off <<= 1) {
        int t = (tid >= off) ? sd[tid - off] : 0;
        __syncthreads();
        sd[tid] += t;
        __syncthreads();
    }
    if (i < n) out[i] = sd[tid] - v;          // exclusive
    if (tid == 0) bsum[blockIdx.x] = sd[1023]; // block total
}

// exclusive scan of up to 128 block sums, in place
__global__ void k_scan2(int* __restrict__ bs, int nb) {
    __shared__ int sd[128];
    int tid = threadIdx.x;
    int v = (tid < nb) ? bs[tid] : 0;
    sd[tid] = v;
    __syncthreads();
    for (int off = 1; off < 128; off <<= 1) {
        int t = (tid >= off) ? sd[tid - off] : 0;
        __syncthreads();
        sd[tid] += t;
        __syncthreads();
    }
    if (tid < nb) bs[tid] = sd[tid] - v;
}

__global__ void k_scan3(const int* __restrict__ scanned, const int* __restrict__ bsum,
                        int n, int E, int* __restrict__ offs, int* __restrict__ cursor) {
    int i = blockIdx.x * blockDim.x + threadIdx.x;
    if (i < n) {
        int o = scanned[i] + bsum[i >> 10];
        offs[i] = o;
        cursor[i] = o;
    }
    if (i == 0) offs[n] = E;
}

__global__ void k_scatter(const int* __restrict__ src, const int* __restrict__ dst, int E,
                          int* __restrict__ cursor, int* __restrict__ adj) {
    int e = blockIdx.x * blockDim.x + threadIdx.x;
    if (e < E) {
        int d = dst[e];
        int p = atomicAdd(&cursor[d], 1);
        adj[p] = src[e];
    }
}

// ---------------- GAT layer kernels ----------------
// One wave (64 lanes) per node; 4 nodes per 256-thread block.

// layer 0 projection: h = concat(pos,x) [N,32] @ W[32,64]; also s = hp.att_src, d = hp.att_dst
__global__ void k_mm0(const float* __restrict__ pos, const float* __restrict__ x,
                      const float* __restrict__ W, const float* __restrict__ asrc,
                      const float* __restrict__ adst, int n, float* __restrict__ hp,
                      float* __restrict__ s, float* __restrict__ d) {
    __shared__ float hs[4][32];
    int tid = threadIdx.x;
    int lane = tid & 63;
    int wv = tid >> 6;
    int node = blockIdx.x * 4 + wv;
    int nd = node < n ? node : n - 1;
    // stage this wave's 32-float input row in its own LDS slot (no cross-wave sync needed)
    if (lane < 2) hs[wv][lane] = pos[(size_t)nd * 2 + lane];
    else if (lane < 32) hs[wv][lane] = x[(size_t)nd * 30 + lane - 2];
    float acc = 0.f;
#pragma unroll
    for (int k = 0; k < 32; k++) acc += hs[wv][k] * W[k * 64 + lane];
    if (node >= n) return;
    hp[(size_t)node * 64 + lane] = acc;
    float sv = acc * asrc[lane];
    float dv = acc * adst[lane];
#pragma unroll
    for (int off = 32; off; off >>= 1) {
        sv += __shfl_xor(sv, off);
        dv += __shfl_xor(dv, off);
    }
    if (lane == 0) {
        s[node] = sv;
        d[node] = dv;
    }
}

// layer 1 projection: h [N,64] @ W[64,64]
__global__ void k_mm(const float* __restrict__ h, const float* __restrict__ W,
                     const float* __restrict__ asrc, const float* __restrict__ adst, int n,
                     float* __restrict__ hp, float* __restrict__ s, float* __restrict__ d) {
    __shared__ float hs[4][64];
    int tid = threadIdx.x;
    int lane = tid & 63;
    int wv = tid >> 6;
    int node = blockIdx.x * 4 + wv;
    int nd = node < n ? node : n - 1;
    hs[wv][lane] = h[(size_t)nd * 64 + lane];
    float acc = 0.f;
#pragma unroll
    for (int k = 0; k < 64; k++) acc += hs[wv][k] * W[k * 64 + lane];
    if (node >= n) return;
    hp[(size_t)node * 64 + lane] = acc;
    float sv = acc * asrc[lane];
    float dv = acc * adst[lane];
#pragma unroll
    for (int off = 32; off; off >>= 1) {
        sv += __shfl_xor(sv, off);
        dv += __shfl_xor(dv, off);
    }
    if (lane == 0) {
        s[node] = sv;
        d[node] = dv;
    }
}

// gather aggregation: softmax over {self} ∪ in-edges, weighted sum of hp rows.
// Edge-lane-parallel weight computation; per-edge fma loop uses readlane (SGPR)
// broadcasts so each edge costs ~4 ops + one coalesced 256B row load.
__global__ void k_agg(const int* __restrict__ offs, const int* __restrict__ adj,
                      const float* __restrict__ hp, const float* __restrict__ s,
                      const float* __restrict__ dd, const float* __restrict__ bias, int n,
                      float* __restrict__ out) {
    int lane = threadIdx.x & 63;
    int node = blockIdx.x * 4 + (threadIdx.x >> 6);
    if (node >= n) return;
    float di = dd[node];
    int e0 = offs[node], e1 = offs[node + 1];
    int deg = e1 - e0;
    int total = deg + 1;  // +1 = self loop (edge index 0)

    float acc = 0.f;
    float wsum;

    if (total <= 64) {
        // ---- fast path: one chunk, everything stays in registers ----
        bool valid = lane < total;
        int j = node;
        if (lane > 0 && valid) j = adj[e0 + lane - 1];
        float sv = valid ? s[j] : -INFINITY;
        float ev = lrelu(sv + di);
        float m = ev;
#pragma unroll
        for (int off = 32; off; off >>= 1) m = fmaxf(m, __shfl_xor(m, off));
        float w = valid ? expf(ev - m) : 0.f;
        float ws = w;
#pragma unroll
        for (int off = 32; off; off >>= 1) ws += __shfl_xor(ws, off);
        wsum = ws;
#pragma unroll 4
        for (int i = 0; i < total; i++) {
            int jj = __shfl(j, i);
            float wi = __shfl(w, i);
            acc += hp[(size_t)jj * 64 + lane] * wi;
        }
    } else {
        // ---- general path: chunked (rare; only for degree > 63) ----
        float m = -INFINITY;
        for (int base = 0; base < total; base += 64) {
            int idx = base + lane;
            bool valid = idx < total;
            int j = node;
            if (idx > 0 && valid) j = adj[e0 + idx - 1];
            float sv = valid ? s[j] : -INFINITY;
            m = fmaxf(m, lrelu(sv + di));
        }
#pragma unroll
        for (int off = 32; off; off >>= 1) m = fmaxf(m, __shfl_xor(m, off));
        float ws = 0.f;
        for (int base = 0; base < total; base += 64) {
            int idx = base + lane;
            bool valid = idx < total;
            int j = node;
            if (idx > 0 && valid) j = adj[e0 + idx - 1];
            float sv = valid ? s[j] : -INFINITY;
            float w = valid ? expf(lrelu(sv + di) - m) : 0.f;
            ws += w;
            int cnt = total - base < 64 ? total - base : 64;
#pragma unroll 4
            for (int i = 0; i < cnt; i++) {
                int jj = __shfl(j, i);
                float wi = __shfl(w, i);
                acc += hp[(size_t)jj * 64 + lane] * wi;
            }
        }
#pragma unroll
        for (int off = 32; off; off >>= 1) ws += __shfl_xor(ws, off);
        wsum = ws;
    }
    out[(size_t)node * 64 + lane] = acc / wsum + bias[lane];
}

// ---------------- pooling + head ----------------

__global__ void k_pool(const float* __restrict__ h, const int* __restrict__ batch, int n,
                       float* __restrict__ out) {
    __shared__ float red[256];
    int gid = blockIdx.x;
    int tid = threadIdx.x;
    int lane = tid & 63;
    int wv = tid >> 6;
    // lower_bound(batch, gid) and lower_bound(batch, gid+1); batch is sorted
    int lo = 0, hi = n;
    while (lo < hi) {
        int md = (lo + hi) >> 1;
        if (batch[md] < gid) lo = md + 1; else hi = md;
    }
    int start = lo;
    lo = 0; hi = n;
    while (lo < hi) {
        int md = (lo + hi) >> 1;
        if (batch[md] < gid + 1) lo = md + 1; else hi = md;
    }
    int end = lo;
    float acc = 0.f;
    for (int i = start + wv; i < end; i += 4) acc += h[(size_t)i * 64 + lane];
    red[tid] = acc;
    __syncthreads();
    if (tid < 64) {
        float sum = red[tid] + red[tid + 64] + red[tid + 128] + red[tid + 192];
        float cnt = (float)(end - start);
        out[gid * 64 + tid] = sum / fmaxf(cnt, 1.f);
    }
}

__global__ void k_head(const float* __restrict__ g, const float* __restrict__ W0,
                       const float* __restrict__ b0, const float* __restrict__ W1,
                       const float* __restrict__ b1, float* __restrict__ out) {
    __shared__ float gs[64];
    __shared__ float mid[32];
    int i = blockIdx.x;
    int t = threadIdx.x;
    gs[t] = g[i * 64 + t];
    __syncthreads();
    if (t < 32) {
        float a = b0[t];
#pragma unroll
        for (int k = 0; k < 64; k++) a += gs[k] * W0[k * 32 + t];
        mid[t] = fmaxf(a, 0.f);
    }
    __syncthreads();
    if (t < 10) {
        float a = b1[t];
#pragma unroll
        for (int k = 0; k < 32; k++) a += mid[k] * W1[k * 10 + t];
        out[i * 10 + t] = fmaxf(a, 0.f);
    }
}

// ---------------- launch ----------------

extern "C" void kernel_launch(void* const* d_in, const int* in_sizes, int n_in,
                              void* d_out, int out_size, void* d_ws, size_t ws_size,
                              hipStream_t stream) {
    const float* x    = (const float*)d_in[0];
    const float* pos  = (const float*)d_in[1];
    const int*   ei   = (const int*)d_in[2];
    const int*   batch= (const int*)d_in[3];
    const float* g0W  = (const float*)d_in[4];
    const float* g0as = (const float*)d_in[5];
    const float* g0ad = (const float*)d_in[6];
    const float* g0b  = (const float*)d_in[7];
    const float* g1W  = (const float*)d_in[8];
    const float* g1as = (const float*)d_in[9];
    const float* g1ad = (const float*)d_in[10];
    const float* g1b  = (const float*)d_in[11];
    const float* l0W  = (const float*)d_in[12];
    const float* l0b  = (const float*)d_in[13];
    const float* l1W  = (const float*)d_in[14];
    const float* l1b  = (const float*)d_in[15];
    float* out = (float*)d_out;

    const int N = in_sizes[3];       // 100000
    const int E = in_sizes[2] / 2;   // 1600000
    const int G = out_size / 10;     // 64

    // workspace carve-up (256B aligned)
    char* w = (char*)d_ws;
    auto alloc = [&](size_t bytes) {
        void* p = (void*)w;
        w += (bytes + 255) & ~(size_t)255;
        return p;
    };
    int* deg     = (int*)alloc((size_t)N * 4);
    int* scanned = (int*)alloc((size_t)N * 4);
    int* bsum    = (int*)alloc(128 * 4);
    int* offs    = (int*)alloc((size_t)(N + 1) * 4);
    int* cursor  = (int*)alloc((size_t)N * 4);
    int* adj     = (int*)alloc((size_t)E * 4);
    float* hp    = (float*)alloc((size_t)N * 64 * 4);
    float* hbuf  = (float*)alloc((size_t)N * 64 * 4);
    float* sarr  = (float*)alloc((size_t)N * 4);
    float* darr  = (float*)alloc((size_t)N * 4);
    float* gpool = (float*)alloc((size_t)G * 64 * 4);

    const int* esrc = ei;
    const int* edst = ei + E;

    // CSR build (shared by both layers)
    hipMemsetAsync(deg, 0, (size_t)N * 4, stream);
    k_deg<<<(E + 255) / 256, 256, 0, stream>>>(edst, E, deg);
    int nb1 = (N + 1023) / 1024; // 98 <= 128 for N=100000
    k_scan1<<<nb1, 1024, 0, stream>>>(deg, N, scanned, bsum);
    k_scan2<<<1, 128, 0, stream>>>(bsum, nb1);
    k_scan3<<<(N + 255) / 256, 256, 0, stream>>>(scanned, bsum, N, E, offs, cursor);
    k_scatter<<<(E + 255) / 256, 256, 0, stream>>>(esrc, edst, E, cursor, adj);

    int nodeBlocks = (N + 3) / 4;
    // layer 0
    k_mm0<<<nodeBlocks, 256, 0, stream>>>(pos, x, g0W, g0as, g0ad, N, hp, sarr, darr);
    k_agg<<<nodeBlocks, 256, 0, stream>>>(offs, adj, hp, sarr, darr, g0b, N, hbuf);
    // layer 1
    k_mm<<<nodeBlocks, 256, 0, stream>>>(hbuf, g1W, g1as, g1ad, N, hp, sarr, darr);
    k_agg<<<nodeBlocks, 256, 0, stream>>>(offs, adj, hp, sarr, darr, g1b, N, hbuf);
    // pool + head
    k_pool<<<G, 256, 0, stream>>>(hbuf, batch, N, gpool);
    k_head<<<G, 64, 0, stream>>>(gpool, l0W, l0b, l1W, l1b, out);
}

// Round 3
// 591.621 us; speedup vs baseline: 1.7035x; 1.2065x over previous
//
#include <hip/hip_runtime.h>

#define NEG_SLOPE 0.2f

__device__ __forceinline__ float lrelu(float x) { return x > 0.f ? x : NEG_SLOPE * x; }

// ---------------- CSR build via bucketed counting sort ----------------
// bucket b = dst >> 8  (256 nodes per bucket, NB = ceil(N/256) buckets)

// per-block LDS histogram of edge buckets -> global bucket counts
__global__ void k_hist(const int* __restrict__ dst, int E, int NB, int* __restrict__ bCnt) {
    __shared__ int h[400];
    int t = threadIdx.x;
    for (int i = t; i < NB; i += 256) h[i] = 0;
    __syncthreads();
    int e0 = blockIdx.x * 2048;
#pragma unroll
    for (int i = 0; i < 8; i++) {
        int e = e0 + i * 256 + t;
        if (e < E) atomicAdd(&h[dst[e] >> 8], 1);
    }
    __syncthreads();
    for (int i = t; i < NB; i += 256)
        if (h[i]) atomicAdd(&bCnt[i], h[i]);
}

// exclusive scan of NB (<512) bucket counts; init bOff and bCur
__global__ void k_bscan(const int* __restrict__ bCnt, int NB, int E,
                        int* __restrict__ bOff, int* __restrict__ bCur) {
    __shared__ int sd[512];
    int t = threadIdx.x;
    int v = (t < NB) ? bCnt[t] : 0;
    sd[t] = v;
    __syncthreads();
    for (int off = 1; off < 512; off <<= 1) {
        int add = (t >= off) ? sd[t - off] : 0;
        __syncthreads();
        sd[t] += add;
        __syncthreads();
    }
    if (t < NB) {
        int ex = sd[t] - v;
        bOff[t] = ex;
        bCur[t] = ex;
    }
    if (t == 0) bOff[NB] = E;
}

// bin (src,dst) pairs into bucket-contiguous regions of ePack
__global__ void k_bin(const int* __restrict__ src, const int* __restrict__ dst, int E, int NB,
                      int* __restrict__ bCur, int2* __restrict__ ePack) {
    __shared__ int h[400];
    __shared__ int base[400];
    int t = threadIdx.x;
    for (int i = t; i < NB; i += 256) h[i] = 0;
    __syncthreads();
    int e0 = blockIdx.x * 2048;
    int2 ed[8];
    int bk[8];
#pragma unroll
    for (int i = 0; i < 8; i++) {
        int e = e0 + i * 256 + t;
        if (e < E) {
            int s_ = src[e], d_ = dst[e];
            ed[i] = make_int2(s_, d_);
            bk[i] = d_ >> 8;
            atomicAdd(&h[bk[i]], 1);
        } else
            bk[i] = -1;
    }
    __syncthreads();
    for (int i = t; i < NB; i += 256) {
        int c = h[i];
        base[i] = c ? atomicAdd(&bCur[i], c) : 0;
        h[i] = 0;
    }
    __syncthreads();
#pragma unroll
    for (int i = 0; i < 8; i++) {
        if (bk[i] >= 0) {
            int p = base[bk[i]] + atomicAdd(&h[bk[i]], 1);
            ePack[p] = ed[i];
        }
    }
}

// one block per bucket: build offs + adj for the bucket's 256 nodes from its packed edges
__global__ void k_csr(const int2* __restrict__ ePack, const int* __restrict__ bOff, int N,
                      int E, int NB, int* __restrict__ offs, int* __restrict__ adj) {
    const int CAP = 4608;
    __shared__ int2 stage[4608];
    __shared__ int cnt[256];
    __shared__ int cur[256];
    int b = blockIdx.x;
    int t = threadIdx.x;
    int lo = b << 8;
    int e0 = bOff[b], e1 = bOff[b + 1];
    int ne = e1 - e0;
    cnt[t] = 0;
    __syncthreads();
    for (int i = t; i < ne; i += 256) {
        int2 ed = ePack[e0 + i];
        if (i < CAP) stage[i] = ed;
        atomicAdd(&cnt[ed.y & 255], 1);
    }
    __syncthreads();
    int v = cnt[t];
    __syncthreads();
    for (int off = 1; off < 256; off <<= 1) {
        int add = (t >= off) ? cnt[t - off] : 0;
        __syncthreads();
        cnt[t] += add;
        __syncthreads();
    }
    int excl = cnt[t] - v;
    cur[t] = excl;
    if (lo + t < N) offs[lo + t] = e0 + excl;
    if (b == 0 && t == 0) offs[N] = E;  // (also correct: last bucket end == E)
    __syncthreads();
    for (int i = t; i < ne; i += 256) {
        int2 ed = (i < CAP) ? stage[i] : ePack[e0 + i];
        int p = e0 + atomicAdd(&cur[ed.y & 255], 1);
        adj[p] = ed.x;
    }
}

// ---------------- GAT layer kernels ----------------
// One wave (64 lanes) per node; 4 nodes per 256-thread block.

// layer 0 projection: h = concat(pos,x) [N,32] @ W[32,64]; also s = hp.att_src, d = hp.att_dst
__global__ void k_mm0(const float* __restrict__ pos, const float* __restrict__ x,
                      const float* __restrict__ W, const float* __restrict__ asrc,
                      const float* __restrict__ adst, int n, float* __restrict__ hp,
                      float* __restrict__ s, float* __restrict__ d) {
    __shared__ float hs[4][32];
    int tid = threadIdx.x;
    int lane = tid & 63;
    int wv = tid >> 6;
    int node = blockIdx.x * 4 + wv;
    int nd = node < n ? node : n - 1;
    if (lane < 2) hs[wv][lane] = pos[(size_t)nd * 2 + lane];
    else if (lane < 32) hs[wv][lane] = x[(size_t)nd * 30 + lane - 2];
    float acc = 0.f;
#pragma unroll
    for (int k = 0; k < 32; k++) acc += hs[wv][k] * W[k * 64 + lane];
    if (node >= n) return;
    hp[(size_t)node * 64 + lane] = acc;
    float sv = acc * asrc[lane];
    float dv = acc * adst[lane];
#pragma unroll
    for (int off = 32; off; off >>= 1) {
        sv += __shfl_xor(sv, off);
        dv += __shfl_xor(dv, off);
    }
    if (lane == 0) {
        s[node] = sv;
        d[node] = dv;
    }
}

// layer 1 projection: h [N,64] @ W[64,64]
__global__ void k_mm(const float* __restrict__ h, const float* __restrict__ W,
                     const float* __restrict__ asrc, const float* __restrict__ adst, int n,
                     float* __restrict__ hp, float* __restrict__ s, float* __restrict__ d) {
    __shared__ float hs[4][64];
    int tid = threadIdx.x;
    int lane = tid & 63;
    int wv = tid >> 6;
    int node = blockIdx.x * 4 + wv;
    int nd = node < n ? node : n - 1;
    hs[wv][lane] = h[(size_t)nd * 64 + lane];
    float acc = 0.f;
#pragma unroll
    for (int k = 0; k < 64; k++) acc += hs[wv][k] * W[k * 64 + lane];
    if (node >= n) return;
    hp[(size_t)node * 64 + lane] = acc;
    float sv = acc * asrc[lane];
    float dv = acc * adst[lane];
#pragma unroll
    for (int off = 32; off; off >>= 1) {
        sv += __shfl_xor(sv, off);
        dv += __shfl_xor(dv, off);
    }
    if (lane == 0) {
        s[node] = sv;
        d[node] = dv;
    }
}

// gather aggregation: softmax over {self} ∪ in-edges, weighted sum of hp rows.
__global__ void k_agg(const int* __restrict__ offs, const int* __restrict__ adj,
                      const float* __restrict__ hp, const float* __restrict__ s,
                      const float* __restrict__ dd, const float* __restrict__ bias, int n,
                      float* __restrict__ out) {
    int lane = threadIdx.x & 63;
    int node = blockIdx.x * 4 + (threadIdx.x >> 6);
    if (node >= n) return;
    float di = dd[node];
    int e0 = offs[node], e1 = offs[node + 1];
    int deg = e1 - e0;
    int total = deg + 1;  // +1 = self loop (lane 0)

    float acc = 0.f;
    float wsum;

    if (total <= 64) {
        bool valid = lane < total;
        int j = node;
        if (lane > 0 && valid) j = adj[e0 + lane - 1];
        float sv = valid ? s[j] : -INFINITY;
        float ev = lrelu(sv + di);
        float m = ev;
#pragma unroll
        for (int off = 32; off; off >>= 1) m = fmaxf(m, __shfl_xor(m, off));
        float w = valid ? expf(ev - m) : 0.f;
        float ws = w;
#pragma unroll
        for (int off = 32; off; off >>= 1) ws += __shfl_xor(ws, off);
        wsum = ws;
#pragma unroll 4
        for (int i = 0; i < total; i++) {
            int jj = __shfl(j, i);
            float wi = __shfl(w, i);
            acc += hp[(size_t)jj * 64 + lane] * wi;
        }
    } else {
        float m = -INFINITY;
        for (int base = 0; base < total; base += 64) {
            int idx = base + lane;
            bool valid = idx < total;
            int j = node;
            if (idx > 0 && valid) j = adj[e0 + idx - 1];
            float sv = valid ? s[j] : -INFINITY;
            m = fmaxf(m, lrelu(sv + di));
        }
#pragma unroll
        for (int off = 32; off; off >>= 1) m = fmaxf(m, __shfl_xor(m, off));
        float ws = 0.f;
        for (int base = 0; base < total; base += 64) {
            int idx = base + lane;
            bool valid = idx < total;
            int j = node;
            if (idx > 0 && valid) j = adj[e0 + idx - 1];
            float sv = valid ? s[j] : -INFINITY;
            float w = valid ? expf(lrelu(sv + di) - m) : 0.f;
            ws += w;
            int cnt = total - base < 64 ? total - base : 64;
#pragma unroll 4
            for (int i = 0; i < cnt; i++) {
                int jj = __shfl(j, i);
                float wi = __shfl(w, i);
                acc += hp[(size_t)jj * 64 + lane] * wi;
            }
        }
#pragma unroll
        for (int off = 32; off; off >>= 1) ws += __shfl_xor(ws, off);
        wsum = ws;
    }
    out[(size_t)node * 64 + lane] = acc / wsum + bias[lane];
}

// ---------------- pooling + head ----------------

__global__ void k_pool(const float* __restrict__ h, const int* __restrict__ batch, int n,
                       float* __restrict__ out) {
    __shared__ float red[256];
    int gid = blockIdx.x;
    int tid = threadIdx.x;
    int lane = tid & 63;
    int wv = tid >> 6;
    int lo = 0, hi = n;
    while (lo < hi) {
        int md = (lo + hi) >> 1;
        if (batch[md] < gid) lo = md + 1; else hi = md;
    }
    int start = lo;
    lo = 0; hi = n;
    while (lo < hi) {
        int md = (lo + hi) >> 1;
        if (batch[md] < gid + 1) lo = md + 1; else hi = md;
    }
    int end = lo;
    float acc = 0.f;
    for (int i = start + wv; i < end; i += 4) acc += h[(size_t)i * 64 + lane];
    red[tid] = acc;
    __syncthreads();
    if (tid < 64) {
        float sum = red[tid] + red[tid + 64] + red[tid + 128] + red[tid + 192];
        float cnt = (float)(end - start);
        out[gid * 64 + tid] = sum / fmaxf(cnt, 1.f);
    }
}

__global__ void k_head(const float* __restrict__ g, const float* __restrict__ W0,
                       const float* __restrict__ b0, const float* __restrict__ W1,
                       const float* __restrict__ b1, float* __restrict__ out) {
    __shared__ float gs[64];
    __shared__ float mid[32];
    int i = blockIdx.x;
    int t = threadIdx.x;
    gs[t] = g[i * 64 + t];
    __syncthreads();
    if (t < 32) {
        float a = b0[t];
#pragma unroll
        for (int k = 0; k < 64; k++) a += gs[k] * W0[k * 32 + t];
        mid[t] = fmaxf(a, 0.f);
    }
    __syncthreads();
    if (t < 10) {
        float a = b1[t];
#pragma unroll
        for (int k = 0; k < 32; k++) a += mid[k] * W1[k * 10 + t];
        out[i * 10 + t] = fmaxf(a, 0.f);
    }
}

// ---------------- launch ----------------

extern "C" void kernel_launch(void* const* d_in, const int* in_sizes, int n_in,
                              void* d_out, int out_size, void* d_ws, size_t ws_size,
                              hipStream_t stream) {
    const float* x    = (const float*)d_in[0];
    const float* pos  = (const float*)d_in[1];
    const int*   ei   = (const int*)d_in[2];
    const int*   batch= (const int*)d_in[3];
    const float* g0W  = (const float*)d_in[4];
    const float* g0as = (const float*)d_in[5];
    const float* g0ad = (const float*)d_in[6];
    const float* g0b  = (const float*)d_in[7];
    const float* g1W  = (const float*)d_in[8];
    const float* g1as = (const float*)d_in[9];
    const float* g1ad = (const float*)d_in[10];
    const float* g1b  = (const float*)d_in[11];
    const float* l0W  = (const float*)d_in[12];
    const float* l0b  = (const float*)d_in[13];
    const float* l1W  = (const float*)d_in[14];
    const float* l1b  = (const float*)d_in[15];
    float* out = (float*)d_out;

    const int N = in_sizes[3];       // 100000
    const int E = in_sizes[2] / 2;   // 1600000
    const int G = out_size / 10;     // 64
    const int NB = (N + 255) >> 8;   // 391 buckets of 256 nodes

    // workspace carve-up (256B aligned)
    char* w = (char*)d_ws;
    auto alloc = [&](size_t bytes) {
        void* p = (void*)w;
        w += (bytes + 255) & ~(size_t)255;
        return p;
    };
    int* bCnt    = (int*)alloc((size_t)NB * 4);
    int* bOff    = (int*)alloc((size_t)(NB + 1) * 4);
    int* bCur    = (int*)alloc((size_t)NB * 4);
    int* offs    = (int*)alloc((size_t)(N + 1) * 4);
    int* adj     = (int*)alloc((size_t)E * 4);
    float* hp    = (float*)alloc((size_t)N * 64 * 4);
    float* hbuf  = (float*)alloc((size_t)N * 64 * 4);
    float* sarr  = (float*)alloc((size_t)N * 4);
    float* darr  = (float*)alloc((size_t)N * 4);
    float* gpool = (float*)alloc((size_t)G * 64 * 4);
    int2* ePack  = (int2*)hp;  // alias: consumed by k_csr before k_mm0 writes hp

    const int* esrc = ei;
    const int* edst = ei + E;

    // CSR build (shared by both layers)
    hipMemsetAsync(bCnt, 0, (size_t)NB * 4, stream);
    int eBlocks = (E + 2047) / 2048;  // 782
    k_hist<<<eBlocks, 256, 0, stream>>>(edst, E, NB, bCnt);
    k_bscan<<<1, 512, 0, stream>>>(bCnt, NB, E, bOff, bCur);
    k_bin<<<eBlocks, 256, 0, stream>>>(esrc, edst, E, NB, bCur, ePack);
    k_csr<<<NB, 256, 0, stream>>>(ePack, bOff, N, E, NB, offs, adj);

    int nodeBlocks = (N + 3) / 4;
    // layer 0
    k_mm0<<<nodeBlocks, 256, 0, stream>>>(pos, x, g0W, g0as, g0ad, N, hp, sarr, darr);
    k_agg<<<nodeBlocks, 256, 0, stream>>>(offs, adj, hp, sarr, darr, g0b, N, hbuf);
    // layer 1
    k_mm<<<nodeBlocks, 256, 0, stream>>>(hbuf, g1W, g1as, g1ad, N, hp, sarr, darr);
    k_agg<<<nodeBlocks, 256, 0, stream>>>(offs, adj, hp, sarr, darr, g1b, N, hbuf);
    // pool + head
    k_pool<<<G, 256, 0, stream>>>(hbuf, batch, N, gpool);
    k_head<<<G, 64, 0, stream>>>(gpool, l0W, l0b, l1W, l1b, out);
}

// Round 5
// 557.252 us; speedup vs baseline: 1.8086x; 1.0617x over previous
//
#include <hip/hip_runtime.h>

#define NEG_SLOPE 0.2f

__device__ __forceinline__ float lrelu(float x) { return x > 0.f ? x : NEG_SLOPE * x; }

// ================= CSR build: atomic-free bucketed counting sort =================
// bucket b = dst >> 8 (256 nodes/bucket, NB buckets); EPB edges per bin-block, EB blocks.
// cnt[b*EB + blk] = #edges of bin-block blk landing in bucket b   (no global atomics)

__global__ void k_cnt(const int* __restrict__ dst, int E, int NB, int EB,
                      int* __restrict__ cnt) {
    __shared__ int h[400];
    int t = threadIdx.x, blk = blockIdx.x;
    for (int i = t; i < NB; i += 256) h[i] = 0;
    __syncthreads();
    int e0 = blk * 8192;
    for (int i = t; i < 8192; i += 256) {
        int e = e0 + i;
        if (e < E) atomicAdd(&h[dst[e] >> 8], 1);
    }
    __syncthreads();
    for (int i = t; i < NB; i += 256) cnt[i * EB + blk] = h[i];
}

// per-bucket totals
__global__ void k_btot(const int* __restrict__ cnt, int EB, int* __restrict__ tot) {
    __shared__ int sd[256];
    int b = blockIdx.x, t = threadIdx.x;
    int v = 0;
    for (int i = t; i < EB; i += 256) v += cnt[b * EB + i];
    sd[t] = v;
    __syncthreads();
    for (int o = 128; o; o >>= 1) {
        if (t < o) sd[t] += sd[t + o];
        __syncthreads();
    }
    if (!t) tot[b] = sd[0];
}

// exclusive scan of NB (<512) bucket totals -> bOff
__global__ void k_bscan(const int* __restrict__ tot, int NB, int E, int* __restrict__ bOff) {
    __shared__ int sd[512];
    int t = threadIdx.x;
    int v = (t < NB) ? tot[t] : 0;
    sd[t] = v;
    __syncthreads();
    for (int o = 1; o < 512; o <<= 1) {
        int a = (t >= o) ? sd[t - o] : 0;
        __syncthreads();
        sd[t] += a;
        __syncthreads();
    }
    if (t < NB) bOff[t] = sd[t] - v;
    if (t == 0) bOff[NB] = E;
}

// per-(bucket,block) write bases: base[b*EB+blk] = bOff[b] + prefix_blocks(cnt[b][0..blk))
__global__ void k_bbase(const int* __restrict__ cnt, const int* __restrict__ bOff, int EB,
                        int* __restrict__ base) {
    __shared__ int sd[256];
    int b = blockIdx.x, t = threadIdx.x;
    int v = (t < EB) ? cnt[b * EB + t] : 0;
    sd[t] = v;
    __syncthreads();
    for (int o = 1; o < 256; o <<= 1) {
        int a = (t >= o) ? sd[t - o] : 0;
        __syncthreads();
        sd[t] += a;
        __syncthreads();
    }
    if (t < EB) base[b * EB + t] = bOff[b] + sd[t] - v;
}

// rank (LDS atomics only) and write (src,dst) into bucket-contiguous ePack
__global__ void k_bin(const int* __restrict__ src, const int* __restrict__ dst, int E, int NB,
                      int EB, const int* __restrict__ base, int2* __restrict__ ePack) {
    __shared__ int baseL[400];
    __shared__ int h[400];
    int t = threadIdx.x, blk = blockIdx.x;
    for (int i = t; i < NB; i += 256) {
        baseL[i] = base[i * EB + blk];
        h[i] = 0;
    }
    __syncthreads();
    int e0 = blk * 8192;
    for (int i = t; i < 8192; i += 256) {
        int e = e0 + i;
        if (e < E) {
            int s_ = src[e], d_ = dst[e];
            int bk = d_ >> 8;
            int r = atomicAdd(&h[bk], 1);
            ePack[baseL[bk] + r] = make_int2(s_, d_);
        }
    }
}

// one block per bucket: build offs + adj for the bucket's 256 nodes
__global__ void k_csr(const int2* __restrict__ ePack, const int* __restrict__ bOff, int N,
                      int E, int NB, int* __restrict__ offs, int* __restrict__ adj) {
    const int CAP = 4608;
    __shared__ int2 stage[4608];
    __shared__ int cnt[256];
    __shared__ int cur[256];
    int b = blockIdx.x;
    int t = threadIdx.x;
    int lo = b << 8;
    int e0 = bOff[b], e1 = bOff[b + 1];
    int ne = e1 - e0;
    cnt[t] = 0;
    __syncthreads();
    for (int i = t; i < ne; i += 256) {
        int2 ed = ePack[e0 + i];
        if (i < CAP) stage[i] = ed;
        atomicAdd(&cnt[ed.y & 255], 1);
    }
    __syncthreads();
    int v = cnt[t];
    __syncthreads();
    for (int off = 1; off < 256; off <<= 1) {
        int add = (t >= off) ? cnt[t - off] : 0;
        __syncthreads();
        cnt[t] += add;
        __syncthreads();
    }
    int excl = cnt[t] - v;
    cur[t] = excl;
    if (lo + t < N) offs[lo + t] = e0 + excl;
    if (b == 0 && t == 0) offs[N] = E;
    __syncthreads();
    for (int i = t; i < ne; i += 256) {
        int2 ed = (i < CAP) ? stage[i] : ePack[e0 + i];
        int p = e0 + atomicAdd(&cur[ed.y & 255], 1);
        adj[p] = ed.x;
    }
}

// ================= GAT layer kernels =================
// One wave (64 lanes) per node; 4 nodes per 256-thread block.

__global__ void k_mm0(const float* __restrict__ pos, const float* __restrict__ x,
                      const float* __restrict__ W, const float* __restrict__ asrc,
                      const float* __restrict__ adst, int n, float* __restrict__ hp,
                      float* __restrict__ s, float* __restrict__ d) {
    __shared__ float hs[4][32];
    int tid = threadIdx.x;
    int lane = tid & 63;
    int wv = tid >> 6;
    int node = blockIdx.x * 4 + wv;
    int nd = node < n ? node : n - 1;
    if (lane < 2) hs[wv][lane] = pos[(size_t)nd * 2 + lane];
    else if (lane < 32) hs[wv][lane] = x[(size_t)nd * 30 + lane - 2];
    float acc = 0.f;
#pragma unroll
    for (int k = 0; k < 32; k++) acc += hs[wv][k] * W[k * 64 + lane];
    if (node >= n) return;
    hp[(size_t)node * 64 + lane] = acc;
    float sv = acc * asrc[lane];
    float dv = acc * adst[lane];
#pragma unroll
    for (int off = 32; off; off >>= 1) {
        sv += __shfl_xor(sv, off);
        dv += __shfl_xor(dv, off);
    }
    if (lane == 0) {
        s[node] = sv;
        d[node] = dv;
    }
}

__global__ void k_mm(const float* __restrict__ h, const float* __restrict__ W,
                     const float* __restrict__ asrc, const float* __restrict__ adst, int n,
                     float* __restrict__ hp, float* __restrict__ s, float* __restrict__ d) {
    __shared__ float hs[4][64];
    int tid = threadIdx.x;
    int lane = tid & 63;
    int wv = tid >> 6;
    int node = blockIdx.x * 4 + wv;
    int nd = node < n ? node : n - 1;
    hs[wv][lane] = h[(size_t)nd * 64 + lane];
    float acc = 0.f;
#pragma unroll
    for (int k = 0; k < 64; k++) acc += hs[wv][k] * W[k * 64 + lane];
    if (node >= n) return;
    hp[(size_t)node * 64 + lane] = acc;
    float sv = acc * asrc[lane];
    float dv = acc * adst[lane];
#pragma unroll
    for (int off = 32; off; off >>= 1) {
        sv += __shfl_xor(sv, off);
        dv += __shfl_xor(dv, off);
    }
    if (lane == 0) {
        s[node] = sv;
        d[node] = dv;
    }
}

// gather aggregation: softmax over {self} ∪ in-edges, weighted sum of hp rows.
// Scalar (readlane) broadcasts -> saddr-form row loads; unroll 8 for MLP.
__global__ void k_agg(const int* __restrict__ offs, const int* __restrict__ adj,
                      const float* __restrict__ hp, const float* __restrict__ s,
                      const float* __restrict__ dd, const float* __restrict__ bias, int n,
                      float* __restrict__ out) {
    int lane = threadIdx.x & 63;
    int node = blockIdx.x * 4 + (threadIdx.x >> 6);
    if (node >= n) return;
    float di = dd[node];
    int e0 = offs[node], e1 = offs[node + 1];
    int total = e1 - e0 + 1;  // +1 = self loop (lane 0)
    int totalU = __builtin_amdgcn_readfirstlane(total);

    float acc = 0.f;
    float wsum;

    if (totalU <= 64) {
        bool valid = lane < totalU;
        int j = node;
        if (lane > 0 && valid) j = adj[e0 + lane - 1];
        float sv = valid ? s[j] : -INFINITY;
        float ev = lrelu(sv + di);
        float m = ev;
#pragma unroll
        for (int off = 32; off; off >>= 1) m = fmaxf(m, __shfl_xor(m, off));
        float w = valid ? expf(ev - m) : 0.f;
        float ws = w;
#pragma unroll
        for (int off = 32; off; off >>= 1) ws += __shfl_xor(ws, off);
        wsum = ws;
        int wbits = __float_as_int(w);
#pragma unroll 8
        for (int i = 0; i < totalU; i++) {
            int jj = __builtin_amdgcn_readlane(j, i);
            float wi = __int_as_float(__builtin_amdgcn_readlane(wbits, i));
            acc += hp[(size_t)jj * 64 + lane] * wi;
        }
    } else {
        float m = -INFINITY;
        for (int base = 0; base < totalU; base += 64) {
            int idx = base + lane;
            bool valid = idx < totalU;
            int j = node;
            if (idx > 0 && valid) j = adj[e0 + idx - 1];
            float sv = valid ? s[j] : -INFINITY;
            m = fmaxf(m, lrelu(sv + di));
        }
#pragma unroll
        for (int off = 32; off; off >>= 1) m = fmaxf(m, __shfl_xor(m, off));
        float ws = 0.f;
        for (int base = 0; base < totalU; base += 64) {
            int idx = base + lane;
            bool valid = idx < totalU;
            int j = node;
            if (idx > 0 && valid) j = adj[e0 + idx - 1];
            float sv = valid ? s[j] : -INFINITY;
            float w = valid ? expf(lrelu(sv + di) - m) : 0.f;
            ws += w;
            int cU = totalU - base < 64 ? totalU - base : 64;
            int wbits = __float_as_int(w);
#pragma unroll 4
            for (int i = 0; i < cU; i++) {
                int jj = __builtin_amdgcn_readlane(j, i);
                float wi = __int_as_float(__builtin_amdgcn_readlane(wbits, i));
                acc += hp[(size_t)jj * 64 + lane] * wi;
            }
        }
#pragma unroll
        for (int off = 32; off; off >>= 1) ws += __shfl_xor(ws, off);
        wsum = ws;
    }
    out[(size_t)node * 64 + lane] = acc / wsum + bias[lane];
}

// ================= pooling + head =================

__global__ void k_pool(const float* __restrict__ h, const int* __restrict__ batch, int n,
                       float* __restrict__ out) {
    __shared__ float red[256];
    int gid = blockIdx.x;
    int tid = threadIdx.x;
    int lane = tid & 63;
    int wv = tid >> 6;
    int lo = 0, hi = n;
    while (lo < hi) {
        int md = (lo + hi) >> 1;
        if (batch[md] < gid) lo = md + 1; else hi = md;
    }
    int start = lo;
    lo = 0; hi = n;
    while (lo < hi) {
        int md = (lo + hi) >> 1;
        if (batch[md] < gid + 1) lo = md + 1; else hi = md;
    }
    int end = lo;
    float acc = 0.f;
    for (int i = start + wv; i < end; i += 4) acc += h[(size_t)i * 64 + lane];
    red[tid] = acc;
    __syncthreads();
    if (tid < 64) {
        float sum = red[tid] + red[tid + 64] + red[tid + 128] + red[tid + 192];
        float cnt = (float)(end - start);
        out[gid * 64 + tid] = sum / fmaxf(cnt, 1.f);
    }
}

__global__ void k_head(const float* __restrict__ g, const float* __restrict__ W0,
                       const float* __restrict__ b0, const float* __restrict__ W1,
                       const float* __restrict__ b1, float* __restrict__ out) {
    __shared__ float gs[64];
    __shared__ float mid[32];
    int i = blockIdx.x;
    int t = threadIdx.x;
    gs[t] = g[i * 64 + t];
    __syncthreads();
    if (t < 32) {
        float a = b0[t];
#pragma unroll
        for (int k = 0; k < 64; k++) a += gs[k] * W0[k * 32 + t];
        mid[t] = fmaxf(a, 0.f);
    }
    __syncthreads();
    if (t < 10) {
        float a = b1[t];
#pragma unroll
        for (int k = 0; k < 32; k++) a += mid[k] * W1[k * 10 + t];
        out[i * 10 + t] = fmaxf(a, 0.f);
    }
}

// ================= launch =================

extern "C" void kernel_launch(void* const* d_in, const int* in_sizes, int n_in,
                              void* d_out, int out_size, void* d_ws, size_t ws_size,
                              hipStream_t stream) {
    const float* x    = (const float*)d_in[0];
    const float* pos  = (const float*)d_in[1];
    const int*   ei   = (const int*)d_in[2];
    const int*   batch= (const int*)d_in[3];
    const float* g0W  = (const float*)d_in[4];
    const float* g0as = (const float*)d_in[5];
    const float* g0ad = (const float*)d_in[6];
    const float* g0b  = (const float*)d_in[7];
    const float* g1W  = (const float*)d_in[8];
    const float* g1as = (const float*)d_in[9];
    const float* g1ad = (const float*)d_in[10];
    const float* g1b  = (const float*)d_in[11];
    const float* l0W  = (const float*)d_in[12];
    const float* l0b  = (const float*)d_in[13];
    const float* l1W  = (const float*)d_in[14];
    const float* l1b  = (const float*)d_in[15];
    float* out = (float*)d_out;

    const int N = in_sizes[3];       // 100000
    const int E = in_sizes[2] / 2;   // 1600000
    const int G = out_size / 10;     // 64
    const int NB = (N + 255) >> 8;   // 391 buckets of 256 nodes
    const int EB = (E + 8191) / 8192; // 196 bin-blocks (must be <= 256)

    // workspace carve-up (256B aligned)
    char* w = (char*)d_ws;
    auto alloc = [&](size_t bytes) {
        void* p = (void*)w;
        w += (bytes + 255) & ~(size_t)255;
        return p;
    };
    int* tot     = (int*)alloc((size_t)NB * 4);
    int* bOff    = (int*)alloc((size_t)(NB + 1) * 4);
    int* offs    = (int*)alloc((size_t)(N + 1) * 4);
    int* adj     = (int*)alloc((size_t)E * 4);
    float* hp    = (float*)alloc((size_t)N * 64 * 4);
    float* hbuf  = (float*)alloc((size_t)N * 64 * 4);
    float* sarr  = (float*)alloc((size_t)N * 4);
    float* darr  = (float*)alloc((size_t)N * 4);
    float* gpool = (float*)alloc((size_t)G * 64 * 4);
    // aliases into regions that are dead during CSR build:
    int2* ePack = (int2*)hp;                 // consumed by k_csr before k_mm0 writes hp
    int* cnt    = (int*)hbuf;                // cnt[NB*EB], dead before first k_agg writes hbuf
    int* base   = (int*)hbuf + (size_t)NB * EB;

    const int* esrc = ei;
    const int* edst = ei + E;

    // CSR build (shared by both layers) — no global atomics
    k_cnt<<<EB, 256, 0, stream>>>(edst, E, NB, EB, cnt);
    k_btot<<<NB, 256, 0, stream>>>(cnt, EB, tot);
    k_bscan<<<1, 512, 0, stream>>>(tot, NB, E, bOff);
    k_bbase<<<NB, 256, 0, stream>>>(cnt, bOff, EB, base);
    k_bin<<<EB, 256, 0, stream>>>(esrc, edst, E, NB, EB, base, ePack);
    k_csr<<<NB, 256, 0, stream>>>(ePack, bOff, N, E, NB, offs, adj);

    int nodeBlocks = (N + 3) / 4;
    // layer 0
    k_mm0<<<nodeBlocks, 256, 0, stream>>>(pos, x, g0W, g0as, g0ad, N, hp, sarr, darr);
    k_agg<<<nodeBlocks, 256, 0, stream>>>(offs, adj, hp, sarr, darr, g0b, N, hbuf);
    // layer 1
    k_mm<<<nodeBlocks, 256, 0, stream>>>(hbuf, g1W, g1as, g1ad, N, hp, sarr, darr);
    k_agg<<<nodeBlocks, 256, 0, stream>>>(offs, adj, hp, sarr, darr, g1b, N, hbuf);
    // pool + head
    k_pool<<<G, 256, 0, stream>>>(hbuf, batch, N, gpool);
    k_head<<<G, 64, 0, stream>>>(gpool, l0W, l0b, l1W, l1b, out);
}

// Round 6
// 424.467 us; speedup vs baseline: 2.3743x; 1.3128x over previous
//
#include <hip/hip_runtime.h>

#define NEG_SLOPE 0.2f

__device__ __forceinline__ float lrelu(float x) { return x > 0.f ? x : NEG_SLOPE * x; }

// ================= CSR build: atomic-free bucketed counting sort =================
// bucket b = dst >> 8 (256 nodes/bucket, NB buckets); cnt[b*EB + blk] per-block counts.

__global__ void k_cnt(const int* __restrict__ dst, int E, int NB, int EB,
                      int* __restrict__ cnt) {
    __shared__ int h[400];
    int t = threadIdx.x, blk = blockIdx.x;
    for (int i = t; i < NB; i += 256) h[i] = 0;
    __syncthreads();
    int e0 = blk * 8192;
    for (int i = t; i < 8192; i += 256) {
        int e = e0 + i;
        if (e < E) atomicAdd(&h[dst[e] >> 8], 1);
    }
    __syncthreads();
    for (int i = t; i < NB; i += 256) cnt[i * EB + blk] = h[i];
}

__global__ void k_btot(const int* __restrict__ cnt, int EB, int* __restrict__ tot) {
    __shared__ int sd[256];
    int b = blockIdx.x, t = threadIdx.x;
    int v = 0;
    for (int i = t; i < EB; i += 256) v += cnt[b * EB + i];
    sd[t] = v;
    __syncthreads();
    for (int o = 128; o; o >>= 1) {
        if (t < o) sd[t] += sd[t + o];
        __syncthreads();
    }
    if (!t) tot[b] = sd[0];
}

__global__ void k_bscan(const int* __restrict__ tot, int NB, int E, int* __restrict__ bOff) {
    __shared__ int sd[512];
    int t = threadIdx.x;
    int v = (t < NB) ? tot[t] : 0;
    sd[t] = v;
    __syncthreads();
    for (int o = 1; o < 512; o <<= 1) {
        int a = (t >= o) ? sd[t - o] : 0;
        __syncthreads();
        sd[t] += a;
        __syncthreads();
    }
    if (t < NB) bOff[t] = sd[t] - v;
    if (t == 0) bOff[NB] = E;
}

__global__ void k_bbase(const int* __restrict__ cnt, const int* __restrict__ bOff, int EB,
                        int* __restrict__ base) {
    __shared__ int sd[256];
    int b = blockIdx.x, t = threadIdx.x;
    int v = (t < EB) ? cnt[b * EB + t] : 0;
    sd[t] = v;
    __syncthreads();
    for (int o = 1; o < 256; o <<= 1) {
        int a = (t >= o) ? sd[t - o] : 0;
        __syncthreads();
        sd[t] += a;
        __syncthreads();
    }
    if (t < EB) base[b * EB + t] = bOff[b] + sd[t] - v;
}

__global__ void k_bin(const int* __restrict__ src, const int* __restrict__ dst, int E, int NB,
                      int EB, const int* __restrict__ base, int2* __restrict__ ePack) {
    __shared__ int baseL[400];
    __shared__ int h[400];
    int t = threadIdx.x, blk = blockIdx.x;
    for (int i = t; i < NB; i += 256) {
        baseL[i] = base[i * EB + blk];
        h[i] = 0;
    }
    __syncthreads();
    int e0 = blk * 8192;
    for (int i = t; i < 8192; i += 256) {
        int e = e0 + i;
        if (e < E) {
            int s_ = src[e], d_ = dst[e];
            int bk = d_ >> 8;
            int r = atomicAdd(&h[bk], 1);
            ePack[baseL[bk] + r] = make_int2(s_, d_);
        }
    }
}

__global__ void k_csr(const int2* __restrict__ ePack, const int* __restrict__ bOff, int N,
                      int E, int NB, int* __restrict__ offs, int* __restrict__ adj) {
    const int CAP = 4608;
    __shared__ int2 stage[4608];
    __shared__ int cnt[256];
    __shared__ int cur[256];
    int b = blockIdx.x;
    int t = threadIdx.x;
    int lo = b << 8;
    int e0 = bOff[b], e1 = bOff[b + 1];
    int ne = e1 - e0;
    cnt[t] = 0;
    __syncthreads();
    for (int i = t; i < ne; i += 256) {
        int2 ed = ePack[e0 + i];
        if (i < CAP) stage[i] = ed;
        atomicAdd(&cnt[ed.y & 255], 1);
    }
    __syncthreads();
    int v = cnt[t];
    __syncthreads();
    for (int off = 1; off < 256; off <<= 1) {
        int add = (t >= off) ? cnt[t - off] : 0;
        __syncthreads();
        cnt[t] += add;
        __syncthreads();
    }
    int excl = cnt[t] - v;
    cur[t] = excl;
    if (lo + t < N) offs[lo + t] = e0 + excl;
    if (b == 0 && t == 0) offs[N] = E;
    __syncthreads();
    for (int i = t; i < ne; i += 256) {
        int2 ed = (i < CAP) ? stage[i] : ePack[e0 + i];
        int p = e0 + atomicAdd(&cur[ed.y & 255], 1);
        adj[p] = ed.x;
    }
}

// ================= GAT layer kernels =================

__global__ void k_mm0(const float* __restrict__ pos, const float* __restrict__ x,
                      const float* __restrict__ W, const float* __restrict__ asrc,
                      const float* __restrict__ adst, int n, float* __restrict__ hp,
                      float* __restrict__ s, float* __restrict__ d) {
    __shared__ float hs[4][32];
    int tid = threadIdx.x;
    int lane = tid & 63;
    int wv = tid >> 6;
    int node = blockIdx.x * 4 + wv;
    int nd = node < n ? node : n - 1;
    if (lane < 2) hs[wv][lane] = pos[(size_t)nd * 2 + lane];
    else if (lane < 32) hs[wv][lane] = x[(size_t)nd * 30 + lane - 2];
    float acc = 0.f;
#pragma unroll
    for (int k = 0; k < 32; k++) acc += hs[wv][k] * W[k * 64 + lane];
    if (node >= n) return;
    hp[(size_t)node * 64 + lane] = acc;
    float sv = acc * asrc[lane];
    float dv = acc * adst[lane];
#pragma unroll
    for (int off = 32; off; off >>= 1) {
        sv += __shfl_xor(sv, off);
        dv += __shfl_xor(dv, off);
    }
    if (lane == 0) {
        s[node] = sv;
        d[node] = dv;
    }
}

__global__ void k_mm(const float* __restrict__ h, const float* __restrict__ W,
                     const float* __restrict__ asrc, const float* __restrict__ adst, int n,
                     float* __restrict__ hp, float* __restrict__ s, float* __restrict__ d) {
    __shared__ float hs[4][64];
    int tid = threadIdx.x;
    int lane = tid & 63;
    int wv = tid >> 6;
    int node = blockIdx.x * 4 + wv;
    int nd = node < n ? node : n - 1;
    hs[wv][lane] = h[(size_t)nd * 64 + lane];
    float acc = 0.f;
#pragma unroll
    for (int k = 0; k < 64; k++) acc += hs[wv][k] * W[k * 64 + lane];
    if (node >= n) return;
    hp[(size_t)node * 64 + lane] = acc;
    float sv = acc * asrc[lane];
    float dv = acc * adst[lane];
#pragma unroll
    for (int off = 32; off; off >>= 1) {
        sv += __shfl_xor(sv, off);
        dv += __shfl_xor(dv, off);
    }
    if (lane == 0) {
        s[node] = sv;
        d[node] = dv;
    }
}

// gather aggregation: softmax over {self} ∪ in-edges, weighted sum of hp rows.
// Half-wave float2 gather: lanes 0-31 process edge i, lanes 32-63 edge i+1;
// each half-wave covers the full 64-feature row as 32 float2 lanes.
// Invalid lanes hold (j=node, w=0) so odd counts need no branches.
__global__ void k_agg(const int* __restrict__ offs, const int* __restrict__ adj,
                      const float* __restrict__ hp, const float* __restrict__ s,
                      const float* __restrict__ dd, const float* __restrict__ bias, int n,
                      float* __restrict__ out) {
    int lane = threadIdx.x & 63;
    int node = blockIdx.x * 4 + (threadIdx.x >> 6);
    if (node >= n) return;
    int hw = lane >> 5;   // which edge of the pair
    int fl = lane & 31;   // float2 feature index
    const float2* hp2 = (const float2*)hp;
    float di = dd[node];
    int e0 = offs[node], e1 = offs[node + 1];
    int total = e1 - e0 + 1;  // +1 = self loop (lane 0)
    int totalU = __builtin_amdgcn_readfirstlane(total);

    float2 acc = make_float2(0.f, 0.f);
    float wsum;

    if (totalU <= 64) {
        bool valid = lane < totalU;
        int j = node;  // lanes >= total keep j=node (w will be 0)
        if (lane > 0 && valid) j = adj[e0 + lane - 1];
        float sv = valid ? s[j] : -INFINITY;
        float ev = lrelu(sv + di);
        float m = ev;
#pragma unroll
        for (int off = 32; off; off >>= 1) m = fmaxf(m, __shfl_xor(m, off));
        float wgt = valid ? expf(ev - m) : 0.f;
        float ws = wgt;
#pragma unroll
        for (int off = 32; off; off >>= 1) ws += __shfl_xor(ws, off);
        wsum = ws;
        int wbits = __float_as_int(wgt);
#pragma unroll 8
        for (int i = 0; i < totalU; i += 2) {
            int j0 = __builtin_amdgcn_readlane(j, i);
            float w0 = __int_as_float(__builtin_amdgcn_readlane(wbits, i));
            int j1 = __builtin_amdgcn_readlane(j, i + 1);
            float w1 = __int_as_float(__builtin_amdgcn_readlane(wbits, i + 1));
            int jj = hw ? j1 : j0;
            float ww = hw ? w1 : w0;
            float2 r = hp2[(size_t)jj * 32 + fl];
            acc.x += r.x * ww;
            acc.y += r.y * ww;
        }
    } else {
        float m = -INFINITY;
        for (int base = 0; base < totalU; base += 64) {
            int idx = base + lane;
            bool valid = idx < totalU;
            int j = node;
            if (idx > 0 && valid) j = adj[e0 + idx - 1];
            float sv = valid ? s[j] : -INFINITY;
            m = fmaxf(m, lrelu(sv + di));
        }
#pragma unroll
        for (int off = 32; off; off >>= 1) m = fmaxf(m, __shfl_xor(m, off));
        float ws = 0.f;
        for (int base = 0; base < totalU; base += 64) {
            int idx = base + lane;
            bool valid = idx < totalU;
            int j = node;
            if (idx > 0 && valid) j = adj[e0 + idx - 1];
            float sv = valid ? s[j] : -INFINITY;
            float wgt = valid ? expf(lrelu(sv + di) - m) : 0.f;
            ws += wgt;
            int cU = totalU - base < 64 ? totalU - base : 64;
            int wbits = __float_as_int(wgt);
#pragma unroll 4
            for (int i = 0; i < cU; i += 2) {
                int j0 = __builtin_amdgcn_readlane(j, i);
                float w0 = __int_as_float(__builtin_amdgcn_readlane(wbits, i));
                int i1 = i + 1 < 64 ? i + 1 : 63;
                int j1 = __builtin_amdgcn_readlane(j, i1);
                float w1 = __int_as_float(__builtin_amdgcn_readlane(wbits, i1));
                if (i + 1 >= cU) w1 = 0.f;  // guard last odd element of chunk
                int jj = hw ? j1 : j0;
                float ww = hw ? w1 : w0;
                float2 r = hp2[(size_t)jj * 32 + fl];
                acc.x += r.x * ww;
                acc.y += r.y * ww;
            }
        }
#pragma unroll
        for (int off = 32; off; off >>= 1) ws += __shfl_xor(ws, off);
        wsum = ws;
    }
    // combine the two half-wave partial sums
    acc.x += __shfl_xor(acc.x, 32);
    acc.y += __shfl_xor(acc.y, 32);
    if (hw == 0) {
        float2 b2 = ((const float2*)bias)[fl];
        float2 o;
        o.x = acc.x / wsum + b2.x;
        o.y = acc.y / wsum + b2.y;
        ((float2*)out)[(size_t)node * 32 + fl] = o;
    }
}

// ================= pooling + head =================
// pool[] must be zeroed before launch. Each wave owns 64 consecutive nodes;
// batch is sorted, so accumulate in registers and flush once per graph boundary.
__global__ void k_pool1(const float* __restrict__ h, const int* __restrict__ batch, int n,
                        float* __restrict__ pool) {
    int lane = threadIdx.x & 63;
    int wv = threadIdx.x >> 6;
    int base = blockIdx.x * 256 + wv * 64;
    if (base >= n) return;
    int cnt = n - base < 64 ? n - base : 64;
    int bl = batch[base + (lane < cnt ? lane : cnt - 1)];
    int cur = __builtin_amdgcn_readfirstlane(bl);
    float acc = 0.f;
    for (int k = 0; k < cnt; k++) {
        int g = __builtin_amdgcn_readlane(bl, k);
        if (g != cur) {
            atomicAdd(&pool[cur * 64 + lane], acc);
            acc = 0.f;
            cur = g;
        }
        acc += h[(size_t)(base + k) * 64 + lane];
    }
    atomicAdd(&pool[cur * 64 + lane], acc);
}

__global__ void k_head(const float* __restrict__ pool, const int* __restrict__ batch, int n,
                       const float* __restrict__ W0, const float* __restrict__ b0,
                       const float* __restrict__ W1, const float* __restrict__ b1,
                       float* __restrict__ out) {
    __shared__ float gs[64];
    __shared__ float mid[32];
    int i = blockIdx.x;
    int t = threadIdx.x;
    // count = lower_bound(i+1) - lower_bound(i) on sorted batch
    int lo = 0, hi = n;
    while (lo < hi) {
        int md = (lo + hi) >> 1;
        if (batch[md] < i) lo = md + 1; else hi = md;
    }
    int start = lo;
    lo = 0; hi = n;
    while (lo < hi) {
        int md = (lo + hi) >> 1;
        if (batch[md] < i + 1) lo = md + 1; else hi = md;
    }
    float cnt = (float)(lo - start);
    gs[t] = pool[i * 64 + t] / fmaxf(cnt, 1.f);
    __syncthreads();
    if (t < 32) {
        float a = b0[t];
#pragma unroll
        for (int k = 0; k < 64; k++) a += gs[k] * W0[k * 32 + t];
        mid[t] = fmaxf(a, 0.f);
    }
    __syncthreads();
    if (t < 10) {
        float a = b1[t];
#pragma unroll
        for (int k = 0; k < 32; k++) a += mid[k] * W1[k * 10 + t];
        out[i * 10 + t] = fmaxf(a, 0.f);
    }
}

// ================= launch =================

extern "C" void kernel_launch(void* const* d_in, const int* in_sizes, int n_in,
                              void* d_out, int out_size, void* d_ws, size_t ws_size,
                              hipStream_t stream) {
    const float* x    = (const float*)d_in[0];
    const float* pos  = (const float*)d_in[1];
    const int*   ei   = (const int*)d_in[2];
    const int*   batch= (const int*)d_in[3];
    const float* g0W  = (const float*)d_in[4];
    const float* g0as = (const float*)d_in[5];
    const float* g0ad = (const float*)d_in[6];
    const float* g0b  = (const float*)d_in[7];
    const float* g1W  = (const float*)d_in[8];
    const float* g1as = (const float*)d_in[9];
    const float* g1ad = (const float*)d_in[10];
    const float* g1b  = (const float*)d_in[11];
    const float* l0W  = (const float*)d_in[12];
    const float* l0b  = (const float*)d_in[13];
    const float* l1W  = (const float*)d_in[14];
    const float* l1b  = (const float*)d_in[15];
    float* out = (float*)d_out;

    const int N = in_sizes[3];       // 100000
    const int E = in_sizes[2] / 2;   // 1600000
    const int G = out_size / 10;     // 64
    const int NB = (N + 255) >> 8;   // 391 buckets of 256 nodes
    const int EB = (E + 8191) / 8192; // 196 bin-blocks (<= 256)

    // workspace carve-up (256B aligned)
    char* w = (char*)d_ws;
    auto alloc = [&](size_t bytes) {
        void* p = (void*)w;
        w += (bytes + 255) & ~(size_t)255;
        return p;
    };
    int* tot     = (int*)alloc((size_t)NB * 4);
    int* bOff    = (int*)alloc((size_t)(NB + 1) * 4);
    int* offs    = (int*)alloc((size_t)(N + 1) * 4);
    int* adj     = (int*)alloc((size_t)E * 4);
    float* hp    = (float*)alloc((size_t)N * 64 * 4);
    float* hbuf  = (float*)alloc((size_t)N * 64 * 4);
    float* sarr  = (float*)alloc((size_t)N * 4);
    float* darr  = (float*)alloc((size_t)N * 4);
    float* gpool = (float*)alloc((size_t)G * 64 * 4);
    // aliases into regions that are dead during CSR build:
    int2* ePack = (int2*)hp;                 // consumed by k_csr before k_mm0 writes hp
    int* cnt    = (int*)hbuf;                // cnt[NB*EB], dead before first k_agg writes hbuf
    int* base   = (int*)hbuf + (size_t)NB * EB;

    const int* esrc = ei;
    const int* edst = ei + E;

    // CSR build (shared by both layers) — no global atomics
    k_cnt<<<EB, 256, 0, stream>>>(edst, E, NB, EB, cnt);
    k_btot<<<NB, 256, 0, stream>>>(cnt, EB, tot);
    k_bscan<<<1, 512, 0, stream>>>(tot, NB, E, bOff);
    k_bbase<<<NB, 256, 0, stream>>>(cnt, bOff, EB, base);
    k_bin<<<EB, 256, 0, stream>>>(esrc, edst, E, NB, EB, base, ePack);
    k_csr<<<NB, 256, 0, stream>>>(ePack, bOff, N, E, NB, offs, adj);

    int nodeBlocks = (N + 3) / 4;
    // layer 0
    k_mm0<<<nodeBlocks, 256, 0, stream>>>(pos, x, g0W, g0as, g0ad, N, hp, sarr, darr);
    k_agg<<<nodeBlocks, 256, 0, stream>>>(offs, adj, hp, sarr, darr, g0b, N, hbuf);
    // layer 1
    k_mm<<<nodeBlocks, 256, 0, stream>>>(hbuf, g1W, g1as, g1ad, N, hp, sarr, darr);
    k_agg<<<nodeBlocks, 256, 0, stream>>>(offs, adj, hp, sarr, darr, g1b, N, hbuf);
    // pool + head
    hipMemsetAsync(gpool, 0, (size_t)G * 64 * 4, stream);
    k_pool1<<<NB, 256, 0, stream>>>(hbuf, batch, N, gpool);
    k_head<<<G, 64, 0, stream>>>(gpool, batch, N, l0W, l0b, l1W, l1b, out);
}

// Round 7
// 424.169 us; speedup vs baseline: 2.3760x; 1.0007x over previous
//
#include <hip/hip_runtime.h>

#define NEG_SLOPE 0.2f

__device__ __forceinline__ float lrelu(float x) { return x > 0.f ? x : NEG_SLOPE * x; }

// ================= CSR build: atomic-free bucketed counting sort =================
// bucket b = dst >> 8 (256 nodes/bucket, NB buckets); cnt[b*EB + blk] per-block counts.
// Edges packed as (src<<8)|(dst&255)  — valid since N < 2^17 here (src < 2^24 required).

__global__ void k_cnt(const int* __restrict__ dst, int E, int NB, int EB,
                      int* __restrict__ cnt) {
    __shared__ int h[400];
    int t = threadIdx.x, blk = blockIdx.x;
    for (int i = t; i < NB; i += 256) h[i] = 0;
    __syncthreads();
    int e0 = blk * 8192;
    for (int i = t; i < 8192; i += 256) {
        int e = e0 + i;
        if (e < E) atomicAdd(&h[dst[e] >> 8], 1);
    }
    __syncthreads();
    for (int i = t; i < NB; i += 256) cnt[i * EB + blk] = h[i];
}

__global__ void k_btot(const int* __restrict__ cnt, int EB, int* __restrict__ tot) {
    __shared__ int sd[256];
    int b = blockIdx.x, t = threadIdx.x;
    int v = 0;
    for (int i = t; i < EB; i += 256) v += cnt[b * EB + i];
    sd[t] = v;
    __syncthreads();
    for (int o = 128; o; o >>= 1) {
        if (t < o) sd[t] += sd[t + o];
        __syncthreads();
    }
    if (!t) tot[b] = sd[0];
}

__global__ void k_bscan(const int* __restrict__ tot, int NB, int E, int* __restrict__ bOff) {
    __shared__ int sd[512];
    int t = threadIdx.x;
    int v = (t < NB) ? tot[t] : 0;
    sd[t] = v;
    __syncthreads();
    for (int o = 1; o < 512; o <<= 1) {
        int a = (t >= o) ? sd[t - o] : 0;
        __syncthreads();
        sd[t] += a;
        __syncthreads();
    }
    if (t < NB) bOff[t] = sd[t] - v;
    if (t == 0) bOff[NB] = E;
}

__global__ void k_bbase(const int* __restrict__ cnt, const int* __restrict__ bOff, int EB,
                        int* __restrict__ base) {
    __shared__ int sd[256];
    int b = blockIdx.x, t = threadIdx.x;
    int v = (t < EB) ? cnt[b * EB + t] : 0;
    sd[t] = v;
    __syncthreads();
    for (int o = 1; o < 256; o <<= 1) {
        int a = (t >= o) ? sd[t - o] : 0;
        __syncthreads();
        sd[t] += a;
        __syncthreads();
    }
    if (t < EB) base[b * EB + t] = bOff[b] + sd[t] - v;
}

// Block-local LDS counting sort by bucket, then coalesced segment writes of packed edges.
__global__ void k_bin(const int* __restrict__ src, const int* __restrict__ dst, int E,
                      int NB, int EB, const int* __restrict__ base, int* __restrict__ pk) {
    __shared__ int hist[400];   // counts, then reset to cursors
    __shared__ int seg[512];    // block-local exclusive bucket starts
    __shared__ int baseL[400];  // global write base per bucket for this block
    __shared__ unsigned short bkt[8192];
    __shared__ int stage[8192];
    int t = threadIdx.x, blk = blockIdx.x;
    int e0 = blk * 8192;
    int ne = E - e0 < 8192 ? E - e0 : 8192;
    for (int i = t; i < NB; i += 256) {
        hist[i] = 0;
        baseL[i] = base[i * EB + blk];
    }
    __syncthreads();
    for (int i = t; i < ne; i += 256) atomicAdd(&hist[dst[e0 + i] >> 8], 1);
    __syncthreads();
    // inclusive Hillis-Steele scan of hist (padded to 512) using 256 threads
    int a = (t < NB) ? hist[t] : 0;
    int b2 = (t + 256 < NB) ? hist[t + 256] : 0;
    seg[t] = a;
    seg[t + 256] = b2;
    __syncthreads();
    for (int o = 1; o < 512; o <<= 1) {
        int x0 = (t >= o) ? seg[t - o] : 0;
        int x1 = seg[t + 256 - o];  // t+256-o >= 0 for o <= 256
        __syncthreads();
        seg[t] += x0;
        seg[t + 256] += x1;
        __syncthreads();
    }
    seg[t] -= a;         // exclusive
    seg[t + 256] -= b2;
    for (int i = t; i < NB; i += 256) hist[i] = 0;  // reuse as rank cursor
    __syncthreads();
    // rank into LDS, sorted by bucket
    for (int i = t; i < ne; i += 256) {
        int d_ = dst[e0 + i], s_ = src[e0 + i];
        int bk = d_ >> 8;
        int r = atomicAdd(&hist[bk], 1);
        int slot = seg[bk] + r;
        stage[slot] = (s_ << 8) | (d_ & 255);
        bkt[slot] = (unsigned short)bk;
    }
    __syncthreads();
    // sweep in sorted order: consecutive lanes hit consecutive global addrs per segment
    for (int i = t; i < ne; i += 256) {
        int bk = bkt[i];
        pk[baseL[bk] + (i - seg[bk])] = stage[i];
    }
}

// one block per bucket: build offs + adj for the bucket's 256 nodes from packed edges
__global__ void k_csr(const int* __restrict__ pk, const int* __restrict__ bOff, int N,
                      int E, int NB, int* __restrict__ offs, int* __restrict__ adj) {
    const int CAP = 4608;
    __shared__ int stage[4608];
    __shared__ int cnt[256];
    __shared__ int cur[256];
    int b = blockIdx.x;
    int t = threadIdx.x;
    int lo = b << 8;
    int e0 = bOff[b], e1 = bOff[b + 1];
    int ne = e1 - e0;
    cnt[t] = 0;
    __syncthreads();
    for (int i = t; i < ne; i += 256) {
        int v = pk[e0 + i];
        if (i < CAP) stage[i] = v;
        atomicAdd(&cnt[v & 255], 1);
    }
    __syncthreads();
    int v = cnt[t];
    __syncthreads();
    for (int off = 1; off < 256; off <<= 1) {
        int add = (t >= off) ? cnt[t - off] : 0;
        __syncthreads();
        cnt[t] += add;
        __syncthreads();
    }
    int excl = cnt[t] - v;
    cur[t] = excl;
    if (lo + t < N) offs[lo + t] = e0 + excl;
    if (b == 0 && t == 0) offs[N] = E;
    __syncthreads();
    for (int i = t; i < ne; i += 256) {
        int ed = (i < CAP) ? stage[i] : pk[e0 + i];
        int p = e0 + atomicAdd(&cur[ed & 255], 1);
        adj[p] = ed >> 8;
    }
}

// ================= GAT layer kernels =================

__global__ void k_mm0(const float* __restrict__ pos, const float* __restrict__ x,
                      const float* __restrict__ W, const float* __restrict__ asrc,
                      const float* __restrict__ adst, int n, float* __restrict__ hp,
                      float* __restrict__ s, float* __restrict__ d) {
    __shared__ float hs[4][32];
    int tid = threadIdx.x;
    int lane = tid & 63;
    int wv = tid >> 6;
    int node = blockIdx.x * 4 + wv;
    int nd = node < n ? node : n - 1;
    if (lane < 2) hs[wv][lane] = pos[(size_t)nd * 2 + lane];
    else if (lane < 32) hs[wv][lane] = x[(size_t)nd * 30 + lane - 2];
    float acc = 0.f;
#pragma unroll
    for (int k = 0; k < 32; k++) acc += hs[wv][k] * W[k * 64 + lane];
    if (node >= n) return;
    hp[(size_t)node * 64 + lane] = acc;
    float sv = acc * asrc[lane];
    float dv = acc * adst[lane];
#pragma unroll
    for (int off = 32; off; off >>= 1) {
        sv += __shfl_xor(sv, off);
        dv += __shfl_xor(dv, off);
    }
    if (lane == 0) {
        s[node] = sv;
        d[node] = dv;
    }
}

__global__ void k_mm(const float* __restrict__ h, const float* __restrict__ W,
                     const float* __restrict__ asrc, const float* __restrict__ adst, int n,
                     float* __restrict__ hp, float* __restrict__ s, float* __restrict__ d) {
    __shared__ float hs[4][64];
    int tid = threadIdx.x;
    int lane = tid & 63;
    int wv = tid >> 6;
    int node = blockIdx.x * 4 + wv;
    int nd = node < n ? node : n - 1;
    hs[wv][lane] = h[(size_t)nd * 64 + lane];
    float acc = 0.f;
#pragma unroll
    for (int k = 0; k < 64; k++) acc += hs[wv][k] * W[k * 64 + lane];
    if (node >= n) return;
    hp[(size_t)node * 64 + lane] = acc;
    float sv = acc * asrc[lane];
    float dv = acc * adst[lane];
#pragma unroll
    for (int off = 32; off; off >>= 1) {
        sv += __shfl_xor(sv, off);
        dv += __shfl_xor(dv, off);
    }
    if (lane == 0) {
        s[node] = sv;
        d[node] = dv;
    }
}

// gather aggregation: softmax over {self} ∪ in-edges, weighted sum of hp rows.
// Half-wave float2 gather: lanes 0-31 process edge i, lanes 32-63 edge i+1.
__global__ void k_agg(const int* __restrict__ offs, const int* __restrict__ adj,
                      const float* __restrict__ hp, const float* __restrict__ s,
                      const float* __restrict__ dd, const float* __restrict__ bias, int n,
                      float* __restrict__ out) {
    int lane = threadIdx.x & 63;
    int node = blockIdx.x * 4 + (threadIdx.x >> 6);
    if (node >= n) return;
    int hw = lane >> 5;
    int fl = lane & 31;
    const float2* hp2 = (const float2*)hp;
    float di = dd[node];
    int e0 = offs[node], e1 = offs[node + 1];
    int total = e1 - e0 + 1;  // +1 = self loop (lane 0)
    int totalU = __builtin_amdgcn_readfirstlane(total);

    float2 acc = make_float2(0.f, 0.f);
    float wsum;

    if (totalU <= 64) {
        bool valid = lane < totalU;
        int j = node;
        if (lane > 0 && valid) j = adj[e0 + lane - 1];
        float sv = valid ? s[j] : -INFINITY;
        float ev = lrelu(sv + di);
        float m = ev;
#pragma unroll
        for (int off = 32; off; off >>= 1) m = fmaxf(m, __shfl_xor(m, off));
        float wgt = valid ? expf(ev - m) : 0.f;
        float ws = wgt;
#pragma unroll
        for (int off = 32; off; off >>= 1) ws += __shfl_xor(ws, off);
        wsum = ws;
        int wbits = __float_as_int(wgt);
#pragma unroll 8
        for (int i = 0; i < totalU; i += 2) {
            int j0 = __builtin_amdgcn_readlane(j, i);
            float w0 = __int_as_float(__builtin_amdgcn_readlane(wbits, i));
            int j1 = __builtin_amdgcn_readlane(j, i + 1);
            float w1 = __int_as_float(__builtin_amdgcn_readlane(wbits, i + 1));
            int jj = hw ? j1 : j0;
            float ww = hw ? w1 : w0;
            float2 r = hp2[(size_t)jj * 32 + fl];
            acc.x += r.x * ww;
            acc.y += r.y * ww;
        }
    } else {
        float m = -INFINITY;
        for (int base = 0; base < totalU; base += 64) {
            int idx = base + lane;
            bool valid = idx < totalU;
            int j = node;
            if (idx > 0 && valid) j = adj[e0 + idx - 1];
            float sv = valid ? s[j] : -INFINITY;
            m = fmaxf(m, lrelu(sv + di));
        }
#pragma unroll
        for (int off = 32; off; off >>= 1) m = fmaxf(m, __shfl_xor(m, off));
        float ws = 0.f;
        for (int base = 0; base < totalU; base += 64) {
            int idx = base + lane;
            bool valid = idx < totalU;
            int j = node;
            if (idx > 0 && valid) j = adj[e0 + idx - 1];
            float sv = valid ? s[j] : -INFINITY;
            float wgt = valid ? expf(lrelu(sv + di) - m) : 0.f;
            ws += wgt;
            int cU = totalU - base < 64 ? totalU - base : 64;
            int wbits = __float_as_int(wgt);
#pragma unroll 4
            for (int i = 0; i < cU; i += 2) {
                int j0 = __builtin_amdgcn_readlane(j, i);
                float w0 = __int_as_float(__builtin_amdgcn_readlane(wbits, i));
                int i1 = i + 1 < 64 ? i + 1 : 63;
                int j1 = __builtin_amdgcn_readlane(j, i1);
                float w1 = __int_as_float(__builtin_amdgcn_readlane(wbits, i1));
                if (i + 1 >= cU) w1 = 0.f;
                int jj = hw ? j1 : j0;
                float ww = hw ? w1 : w0;
                float2 r = hp2[(size_t)jj * 32 + fl];
                acc.x += r.x * ww;
                acc.y += r.y * ww;
            }
        }
#pragma unroll
        for (int off = 32; off; off >>= 1) ws += __shfl_xor(ws, off);
        wsum = ws;
    }
    acc.x += __shfl_xor(acc.x, 32);
    acc.y += __shfl_xor(acc.y, 32);
    if (hw == 0) {
        float2 b2 = ((const float2*)bias)[fl];
        float2 o;
        o.x = acc.x / wsum + b2.x;
        o.y = acc.y / wsum + b2.y;
        ((float2*)out)[(size_t)node * 32 + fl] = o;
    }
}

// ================= pooling + head =================
__global__ void k_pool1(const float* __restrict__ h, const int* __restrict__ batch, int n,
                        float* __restrict__ pool) {
    int lane = threadIdx.x & 63;
    int wv = threadIdx.x >> 6;
    int base = blockIdx.x * 256 + wv * 64;
    if (base >= n) return;
    int cnt = n - base < 64 ? n - base : 64;
    int bl = batch[base + (lane < cnt ? lane : cnt - 1)];
    int cur = __builtin_amdgcn_readfirstlane(bl);
    float acc = 0.f;
    for (int k = 0; k < cnt; k++) {
        int g = __builtin_amdgcn_readlane(bl, k);
        if (g != cur) {
            atomicAdd(&pool[cur * 64 + lane], acc);
            acc = 0.f;
            cur = g;
        }
        acc += h[(size_t)(base + k) * 64 + lane];
    }
    atomicAdd(&pool[cur * 64 + lane], acc);
}

__global__ void k_head(const float* __restrict__ pool, const int* __restrict__ batch, int n,
                       const float* __restrict__ W0, const float* __restrict__ b0,
                       const float* __restrict__ W1, const float* __restrict__ b1,
                       float* __restrict__ out) {
    __shared__ float gs[64];
    __shared__ float mid[32];
    int i = blockIdx.x;
    int t = threadIdx.x;
    int lo = 0, hi = n;
    while (lo < hi) {
        int md = (lo + hi) >> 1;
        if (batch[md] < i) lo = md + 1; else hi = md;
    }
    int start = lo;
    lo = 0; hi = n;
    while (lo < hi) {
        int md = (lo + hi) >> 1;
        if (batch[md] < i + 1) lo = md + 1; else hi = md;
    }
    float cnt = (float)(lo - start);
    gs[t] = pool[i * 64 + t] / fmaxf(cnt, 1.f);
    __syncthreads();
    if (t < 32) {
        float a = b0[t];
#pragma unroll
        for (int k = 0; k < 64; k++) a += gs[k] * W0[k * 32 + t];
        mid[t] = fmaxf(a, 0.f);
    }
    __syncthreads();
    if (t < 10) {
        float a = b1[t];
#pragma unroll
        for (int k = 0; k < 32; k++) a += mid[k] * W1[k * 10 + t];
        out[i * 10 + t] = fmaxf(a, 0.f);
    }
}

// ================= launch =================

extern "C" void kernel_launch(void* const* d_in, const int* in_sizes, int n_in,
                              void* d_out, int out_size, void* d_ws, size_t ws_size,
                              hipStream_t stream) {
    const float* x    = (const float*)d_in[0];
    const float* pos  = (const float*)d_in[1];
    const int*   ei   = (const int*)d_in[2];
    const int*   batch= (const int*)d_in[3];
    const float* g0W  = (const float*)d_in[4];
    const float* g0as = (const float*)d_in[5];
    const float* g0ad = (const float*)d_in[6];
    const float* g0b  = (const float*)d_in[7];
    const float* g1W  = (const float*)d_in[8];
    const float* g1as = (const float*)d_in[9];
    const float* g1ad = (const float*)d_in[10];
    const float* g1b  = (const float*)d_in[11];
    const float* l0W  = (const float*)d_in[12];
    const float* l0b  = (const float*)d_in[13];
    const float* l1W  = (const float*)d_in[14];
    const float* l1b  = (const float*)d_in[15];
    float* out = (float*)d_out;

    const int N = in_sizes[3];       // 100000
    const int E = in_sizes[2] / 2;   // 1600000
    const int G = out_size / 10;     // 64
    const int NB = (N + 255) >> 8;   // 391 buckets of 256 nodes
    const int EB = (E + 8191) / 8192; // 196 bin-blocks (<= 256)

    char* w = (char*)d_ws;
    auto alloc = [&](size_t bytes) {
        void* p = (void*)w;
        w += (bytes + 255) & ~(size_t)255;
        return p;
    };
    int* tot     = (int*)alloc((size_t)NB * 4);
    int* bOff    = (int*)alloc((size_t)(NB + 1) * 4);
    int* offs    = (int*)alloc((size_t)(N + 1) * 4);
    int* adj     = (int*)alloc((size_t)E * 4);
    float* hp    = (float*)alloc((size_t)N * 64 * 4);
    float* hbuf  = (float*)alloc((size_t)N * 64 * 4);
    float* sarr  = (float*)alloc((size_t)N * 4);
    float* darr  = (float*)alloc((size_t)N * 4);
    float* gpool = (float*)alloc((size_t)G * 64 * 4);
    // aliases into regions dead during CSR build:
    int* pk  = (int*)hp;                    // packed edges, consumed by k_csr before k_mm0
    int* cnt = (int*)hbuf;                  // cnt[NB*EB], dead before first k_agg
    int* base = (int*)hbuf + (size_t)NB * EB;

    const int* esrc = ei;
    const int* edst = ei + E;

    // CSR build (shared by both layers) — no global atomics, coalesced bin writes
    k_cnt<<<EB, 256, 0, stream>>>(edst, E, NB, EB, cnt);
    k_btot<<<NB, 256, 0, stream>>>(cnt, EB, tot);
    k_bscan<<<1, 512, 0, stream>>>(tot, NB, E, bOff);
    k_bbase<<<NB, 256, 0, stream>>>(cnt, bOff, EB, base);
    k_bin<<<EB, 256, 0, stream>>>(esrc, edst, E, NB, EB, base, pk);
    k_csr<<<NB, 256, 0, stream>>>(pk, bOff, N, E, NB, offs, adj);

    int nodeBlocks = (N + 3) / 4;
    // layer 0
    k_mm0<<<nodeBlocks, 256, 0, stream>>>(pos, x, g0W, g0as, g0ad, N, hp, sarr, darr);
    k_agg<<<nodeBlocks, 256, 0, stream>>>(offs, adj, hp, sarr, darr, g0b, N, hbuf);
    // layer 1
    k_mm<<<nodeBlocks, 256, 0, stream>>>(hbuf, g1W, g1as, g1ad, N, hp, sarr, darr);
    k_agg<<<nodeBlocks, 256, 0, stream>>>(offs, adj, hp, sarr, darr, g1b, N, hbuf);
    // pool + head
    hipMemsetAsync(gpool, 0, (size_t)G * 64 * 4, stream);
    k_pool1<<<NB, 256, 0, stream>>>(hbuf, batch, N, gpool);
    k_head<<<G, 64, 0, stream>>>(gpool, batch, N, l0W, l0b, l1W, l1b, out);
}